// Round 6
// baseline (551.894 us; speedup 1.0000x reference)
//
#include <hip/hip_runtime.h>
#include <hip/hip_bf16.h>

typedef __bf16 bf16_t;
typedef __attribute__((ext_vector_type(8))) __bf16 bf16x8;
typedef __attribute__((ext_vector_type(4))) float f32x4;
typedef __attribute__((ext_vector_type(4))) float float4_t;

#define MFMA16(a, b, c) __builtin_amdgcn_mfma_f32_16x16x32_bf16((a), (b), (c), 0, 0, 0)

__device__ __forceinline__ float gelu_fast(float x) {
    // x * sigmoid(1.5958x + 0.07135x^3), exp base-2 folded
    float z = x * fmaf(x * x, -0.1029453f, -2.3022081f);
    float e = __builtin_amdgcn_exp2f(z);
    return x * __builtin_amdgcn_rcpf(1.0f + e);
}

__device__ __forceinline__ int lbound(const int* __restrict__ a, int n, int v) {
    int lo = 0, hi = n;
    while (lo < hi) { int mid = (lo + hi) >> 1; if (a[mid] < v) lo = mid + 1; else hi = mid; }
    return lo;
}

__device__ __forceinline__ int seg_of(const int* __restrict__ rsp, int lo, int hi, int er) {
    while (lo < hi) { int mid = (lo + hi + 1) >> 1; if (rsp[mid] <= er) lo = mid; else hi = mid - 1; }
    return lo;
}

__global__ __launch_bounds__(256, 4)
void nmlp_kernel(const float* __restrict__ in_f, const float* __restrict__ out_f,
                 const float* __restrict__ W1, const float* __restrict__ b1,
                 const float* __restrict__ W2, const float* __restrict__ b2,
                 const int* __restrict__ nbr, const int* __restrict__ rsp,
                 float* __restrict__ out, int M, int E, int epw, int nwaves)
{
    // LDS map: [0,16384) W1 frags bf16, [16384,32768) W2 frags (permuted rows),
    //          [32768,33280) b1 f32[128], [33280,33536) b2 f32[64]
    __shared__ alignas(16) unsigned char lds[33536];
    const int tid = threadIdx.x, lane = tid & 63, wslot = tid >> 6;
    const int g = lane >> 4, c = lane & 15;

    // ---- stage W1 into frag-major layout: frag(t,ks): W1[32ks+8g+j][16t+c], j contiguous ----
    for (int i = 0; i < 32; ++i) {
        int idx = i * 256 + tid;               // 0..8191
        int k = idx >> 7, n = idx & 127;
        int ks = k >> 5, gg = (k >> 3) & 3, j = k & 7, t = n >> 4, cc = n & 15;
        ((bf16_t*)lds)[(((2 * t + ks) * 4 + gg) * 16 + cc) * 8 + j] = (bf16_t)W1[idx];
    }
    // ---- stage W2, rows permuted so GEMM1 output renames directly into GEMM2 B-frags ----
    for (int i = 0; i < 32; ++i) {
        int idx = i * 256 + tid;               // 0..8191
        int l = idx >> 6, o = idx & 63;
        int t = l >> 4, gg = (l >> 2) & 3, j = l & 3;
        int k2 = t >> 1, j2 = (t & 1) * 4 + j, u = o >> 4, cc = o & 15;
        ((bf16_t*)lds)[8192 + (((u * 4 + k2) * 4 + gg) * 16 + cc) * 8 + j2] = (bf16_t)W2[idx];
    }
    if (tid < 128) *(float*)(lds + 32768 + tid * 4) = b1[tid];
    if (tid < 64)  *(float*)(lds + 33280 + tid * 4) = b2[tid];
    __syncthreads();

    const unsigned wbase = (unsigned)lane * 16u;

    const int wid = blockIdx.x * 4 + wslot;
    int sA = lbound(rsp, M + 1, wid * epw);
    int sB = lbound(rsp, M + 1, wid * epw + epw);
    if (sA > M) sA = M;
    if (sB > M) sB = M;
    if (wid == nwaves - 1) sB = M;             // cover trailing empty segments
    if (sA >= sB) return;

    int s = sA, e0c = rsp[s], e1c = rsp[s + 1];
    const int eS = e0c, eE = rsp[sB];

    f32x4 colacc[4];
    #pragma unroll
    for (int u = 0; u < 4; ++u) colacc[u] = (f32x4){0.f, 0.f, 0.f, 0.f};

    // masked accumulate of one 16-edge block + segment closes (all control wave-uniform)
    auto accum_close = [&](int bt, const f32x4* y) {
        const int tend = (bt + 16 < eE) ? bt + 16 : eE;
        const int er = bt + c;                 // this lane's edge id
        while (true) {
            int hi_p = (e1c < tend) ? e1c : tend;
            int lo_p = (e0c > bt) ? e0c : bt;
            float m = (er >= lo_p && er < hi_p) ? 1.0f : 0.0f;
            #pragma unroll
            for (int u = 0; u < 4; ++u)
                #pragma unroll
                for (int j = 0; j < 4; ++j)
                    colacc[u][j] = fmaf(y[u][j], m, colacc[u][j]);
            if (e1c <= tend) {
                const int d = e1c - e0c;
                const float inv = (d > 0) ? __builtin_amdgcn_rcpf((float)d) : 0.0f;
                float* orow = out + (size_t)s * 64;
                #pragma unroll
                for (int u = 0; u < 4; ++u) {
                    const f32x4 b2v = *(const f32x4*)(lds + 33280 + u * 64 + g * 16);
                    #pragma unroll
                    for (int j = 0; j < 4; ++j) {
                        float v = colacc[u][j];
                        v += __shfl_xor(v, 1); v += __shfl_xor(v, 2);
                        v += __shfl_xor(v, 4); v += __shfl_xor(v, 8);
                        if (c == 0) orow[u * 16 + g * 4 + j] = (d > 0) ? fmaf(v, inv, b2v[j]) : 0.0f;
                    }
                    colacc[u] = (f32x4){0.f, 0.f, 0.f, 0.f};
                }
                ++s; e0c = e1c;
                if (s >= sB) break;
                e1c = rsp[s + 1];
            } else break;
        }
    };

    if (eS < eE) {
        // tile-0 prefetch: per-lane edge, neighbor, segment (one-time binary search), rows
        int er = eS + c; if (er > eE - 1) er = eE - 1;
        int nb = nbr[er];
        int sg = seg_of(rsp, s, sB - 1, er);
        float4_t f0, f1, g0, g1;
        { const float4_t* p = (const float4_t*)(in_f  + (size_t)nb * 32 + 8 * g); f0 = p[0]; f1 = p[1]; }
        { const float4_t* p = (const float4_t*)(out_f + (size_t)sg * 32 + 8 * g); g0 = p[0]; g1 = p[1]; }

        for (int et = eS; et < eE; et += 16) {
            // convert arrived features -> B-frags (lane supplies agg[edge c][8g+j])
            bf16x8 a0, a1;
            #pragma unroll
            for (int j = 0; j < 4; ++j) {
                a0[j] = (bf16_t)f0[j]; a0[4 + j] = (bf16_t)f1[j];
                a1[j] = (bf16_t)g0[j]; a1[4 + j] = (bf16_t)g1[j];
            }
            // next tile: index load + cheap linear segment advance (monotone, ~0.5 steps avg)
            const bool more = (et + 16 < eE);
            int nbN = 0, sgN = sg;
            if (more) {
                int erN = et + 16 + c; if (erN > eE - 1) erN = eE - 1;
                nbN = nbr[erN];
                while (sgN < sB - 1 && rsp[sgN + 1] <= erN) ++sgN;
            }
            // ---- GEMM1': h^T = W1^T(LDS frags) x agg^T(regs); GELU; pack to GEMM2 B-frags ----
            bf16x8 ph[4];
            #pragma unroll
            for (int t = 0; t < 8; ++t) {
                const f32x4 b1v  = *(const f32x4*)(lds + 32768 + t * 64 + g * 16);
                const bf16x8 w10 = *(const bf16x8*)(lds + wbase + (2 * t) * 1024);
                const bf16x8 w11 = *(const bf16x8*)(lds + wbase + (2 * t + 1) * 1024);
                f32x4 h = b1v;
                h = MFMA16(w10, a0, h);
                h = MFMA16(w11, a1, h);
                #pragma unroll
                for (int j = 0; j < 4; ++j)
                    ph[t >> 1][(t & 1) * 4 + j] = (bf16_t)gelu_fast(h[j]);
            }
            // issue next tile's row loads (hide under GEMM2); slf reloads only on sg change
            if (more) {
                { const float4_t* p = (const float4_t*)(in_f + (size_t)nbN * 32 + 8 * g); f0 = p[0]; f1 = p[1]; }
                if (sgN != sg) {
                    const float4_t* p = (const float4_t*)(out_f + (size_t)sgN * 32 + 8 * g);
                    g0 = p[0]; g1 = p[1];
                }
                sg = sgN;
            }
            // ---- GEMM2': y^T = W2^T(perm LDS frags) x h^T(regs) ----
            f32x4 y[4];
            #pragma unroll
            for (int u = 0; u < 4; ++u) y[u] = (f32x4){0.f, 0.f, 0.f, 0.f};
            #pragma unroll
            for (int u = 0; u < 4; ++u)
                #pragma unroll
                for (int k2 = 0; k2 < 4; ++k2) {
                    const bf16x8 w2 = *(const bf16x8*)(lds + 16384 + wbase + (u * 4 + k2) * 1024);
                    y[u] = MFMA16(w2, ph[k2], y[u]);
                }
            accum_close(et, y);
        }
    }
    // all-empty range tail
    while (s < sB) {
        float* orow = out + (size_t)s * 64;
        if (c == 0) {
            #pragma unroll
            for (int u = 0; u < 4; ++u)
                #pragma unroll
                for (int j = 0; j < 4; ++j) orow[u * 16 + g * 4 + j] = 0.0f;
        }
        ++s;
    }
}

extern "C" void kernel_launch(void* const* d_in, const int* in_sizes, int n_in,
                              void* d_out, int out_size, void* d_ws, size_t ws_size,
                              hipStream_t stream) {
    const float* in_f  = (const float*)d_in[0];
    const float* out_f = (const float*)d_in[1];
    const float* W1    = (const float*)d_in[2];
    const float* b1    = (const float*)d_in[3];
    const float* W2    = (const float*)d_in[4];
    const float* b2    = (const float*)d_in[5];
    const int*   nbr   = (const int*)d_in[6];
    const int*   rsp   = (const int*)d_in[7];
    float* out = (float*)d_out;
    const int M = in_sizes[7] - 1;
    const int E = in_sizes[6];

    const int nblocks = 1024;             // 4 blocks/CU resident -> 4 waves/SIMD (LDS 135K/CU)
    const int nwaves  = nblocks * 4;
    const int epw = (E + nwaves - 1) / nwaves;

    nmlp_kernel<<<dim3(nblocks), dim3(256), 0, stream>>>(in_f, out_f, W1, b1, W2, b2,
                                                         nbr, rsp, out, M, E, epw, nwaves);
}

// Round 9
// 200.323 us; speedup vs baseline: 2.7550x; 2.7550x over previous
//
#include <hip/hip_runtime.h>
#include <hip/hip_bf16.h>

typedef __bf16 bf16_t;
typedef __attribute__((ext_vector_type(8))) __bf16 bf16x8;
typedef __attribute__((ext_vector_type(4))) float f32x4;
typedef __attribute__((ext_vector_type(4))) float float4_t;

#define MFMA16(a, b, c) __builtin_amdgcn_mfma_f32_16x16x32_bf16((a), (b), (c), 0, 0, 0)

__device__ __forceinline__ float gelu_fast(float x) {
    float z = x * fmaf(x * x, -0.1029453f, -2.3022081f);
    float e = __builtin_amdgcn_exp2f(z);
    return x * __builtin_amdgcn_rcpf(1.0f + e);
}

__device__ __forceinline__ int lbound(const int* __restrict__ a, int n, int v) {
    int lo = 0, hi = n;
    while (lo < hi) { int mid = (lo + hi) >> 1; if (a[mid] < v) lo = mid + 1; else hi = mid; }
    return lo;
}

__device__ __forceinline__ int seg_of(const int* __restrict__ rsp, int lo, int hi, int er) {
    while (lo < hi) { int mid = (lo + hi + 1) >> 1; if (rsp[mid] <= er) lo = mid; else hi = mid - 1; }
    return lo;
}

__global__ __launch_bounds__(256, 2)
void nmlp_kernel(const float* __restrict__ in_f, const float* __restrict__ out_f,
                 const float* __restrict__ W1, const float* __restrict__ b1,
                 const float* __restrict__ W2, const float* __restrict__ b2,
                 const int* __restrict__ nbr, const int* __restrict__ rsp,
                 float* __restrict__ out, int M, int E, int epw, int nwaves)
{
    // LDS map (bytes):
    //   [0, 16384)      W2 frags bf16 (16 frags x 1024B)
    //   [16384, 51200)  per-wave h double-buffers: wave w at 16384 + w*8704, 2 x 4352B
    //   W1 fp32 staged TEMPORARILY at [16384, 49152) (dead before h buffers first used)
    __shared__ alignas(16) unsigned char lds[51200];
    const int tid = threadIdx.x, lane = tid & 63, wslot = tid >> 6;
    const int g = lane >> 4, c = lane & 15;

    // phase 1: W1 fp32 -> [16384,49152); W2 -> frag layout at [0,16384). Disjoint.
    {
        const float4_t* src = (const float4_t*)W1;
        float4_t* dst = (float4_t*)(lds + 16384);
        #pragma unroll
        for (int i = 0; i < 8; ++i) dst[tid + 256 * i] = src[tid + 256 * i];
    }
    for (int i = 0; i < 32; ++i) {
        int idx = i * 256 + tid;               // 0..8191
        int l = idx >> 6, o = idx & 63;
        int k2 = l >> 5, gg = (l >> 3) & 3, j = l & 7, u = o >> 4, cc = o & 15;
        // frag(u,k2): lane gg*16+cc holds W2[32k2+8gg+j][16u+cc], j contiguous
        ((bf16_t*)lds)[((u * 4 + k2) * 64 + gg * 16 + cc) * 8 + j] = (bf16_t)W2[idx];
    }
    __syncthreads();
    // phase 2: W1 regs from staging
    const float* w1s = (const float*)(lds + 16384);
    bf16x8 w1f[8][2];   // [t][k]: W1[32k+8g+j][16t+c]
    #pragma unroll
    for (int t = 0; t < 8; ++t)
        #pragma unroll
        for (int k = 0; k < 2; ++k)
            #pragma unroll
            for (int j = 0; j < 8; ++j)
                w1f[t][k][j] = (bf16_t)w1s[(32 * k + 8 * g + j) * 128 + 16 * t + c];
    __syncthreads();   // staging area becomes h buffers

    float b1r[8], b2r[4];
    #pragma unroll
    for (int t = 0; t < 8; ++t) b1r[t] = b1[16 * t + c];
    #pragma unroll
    for (int u = 0; u < 4; ++u) b2r[u] = b2[16 * u + c];

    // h buffers: 16 rows x 272B stride
    const unsigned hA = 16384u + (unsigned)wslot * 8704u;
    const unsigned hBf = hA + 4352u;
    const unsigned hwA = hA + (unsigned)(g * 1088 + 2 * c);   // + j*272 + t*32
    const unsigned hwB = hBf + (unsigned)(g * 1088 + 2 * c);
    const unsigned hrA = hA + (unsigned)(c * 272 + 16 * g);   // + k2*64
    const unsigned hrB = hBf + (unsigned)(c * 272 + 16 * g);

    const int wid = blockIdx.x * 4 + wslot;
    int sA_ = lbound(rsp, M + 1, wid * epw);
    int sB = lbound(rsp, M + 1, wid * epw + epw);
    if (sA_ > M) sA_ = M;
    if (sB > M) sB = M;
    if (wid == nwaves - 1) sB = M;
    if (sA_ >= sB) return;

    int s = sA_, e0c = rsp[s], e1c = rsp[s + 1];
    const int eS = e0c, eE = rsp[sB];

    f32x4 colacc[4];
    #pragma unroll
    for (int u = 0; u < 4; ++u) colacc[u] = (f32x4){0.f, 0.f, 0.f, 0.f};

    // masked accumulate + segment closes for one 16-edge block.
    // Unswapped D-layout: edge within tile = D-row = 4g+j; c = output channel.
    auto accum_close = [&](int bt, const f32x4* y) {
        const int tend = (bt + 16 < eE) ? bt + 16 : eE;
        while (true) {
            int hi_p = (e1c < tend) ? e1c : tend;
            int lo_p = (e0c > bt) ? e0c : bt;
            #pragma unroll
            for (int j = 0; j < 4; ++j) {
                const int er = bt + 4 * g + j;          // this row's edge id
                const float m = (er >= lo_p && er < hi_p) ? 1.0f : 0.0f;
                #pragma unroll
                for (int u = 0; u < 4; ++u)
                    colacc[u][j] = fmaf(y[u][j], m, colacc[u][j]);
            }
            if (e1c <= tend) {
                const int d = e1c - e0c;
                const float inv = (d > 0) ? __builtin_amdgcn_rcpf((float)d) : 0.0f;
                float* orow = out + (size_t)s * 64;
                #pragma unroll
                for (int u = 0; u < 4; ++u) {
                    float v = colacc[u][0] + colacc[u][1] + colacc[u][2] + colacc[u][3];
                    v += __shfl_xor(v, 16); v += __shfl_xor(v, 32);
                    if (g == 0) orow[u * 16 + c] = (d > 0) ? fmaf(v, inv, b2r[u]) : 0.0f;
                    colacc[u] = (f32x4){0.f, 0.f, 0.f, 0.f};
                }
                ++s; e0c = e1c;
                if (s >= sB) break;
                e1c = rsp[s + 1];
            } else break;
        }
    };

    if (eS < eE) {
        int erA = eS + c;      if (erA > eE - 1) erA = eE - 1;
        int erB = eS + 16 + c; if (erB > eE - 1) erB = eE - 1;
        int nbA = nbr[erA], nbB = nbr[erB];
        int sgA = seg_of(rsp, s, sB - 1, erA);
        int sgB = sgA;
        while (sgB < sB - 1 && rsp[sgB + 1] <= erB) ++sgB;
        float4_t fA0, fA1, gA0, gA1, fB0, fB1, gB0, gB1;
        { const float4_t* p = (const float4_t*)(in_f  + (size_t)nbA * 32 + 8 * g); fA0 = p[0]; fA1 = p[1]; }
        { const float4_t* p = (const float4_t*)(out_f + (size_t)sgA * 32 + 8 * g); gA0 = p[0]; gA1 = p[1]; }
        { const float4_t* p = (const float4_t*)(in_f  + (size_t)nbB * 32 + 8 * g); fB0 = p[0]; fB1 = p[1]; }
        { const float4_t* p = (const float4_t*)(out_f + (size_t)sgB * 32 + 8 * g); gB0 = p[0]; gB1 = p[1]; }

        for (int et = eS; et < eE; et += 32) {
            // convert arrived rows -> A-frags for both tiles
            bf16x8 aA0, aA1, aB0, aB1;
            #pragma unroll
            for (int j = 0; j < 4; ++j) {
                aA0[j] = (bf16_t)fA0[j]; aA0[4 + j] = (bf16_t)fA1[j];
                aA1[j] = (bf16_t)gA0[j]; aA1[4 + j] = (bf16_t)gA1[j];
                aB0[j] = (bf16_t)fB0[j]; aB0[4 + j] = (bf16_t)fB1[j];
                aB1[j] = (bf16_t)gB0[j]; aB1[4 + j] = (bf16_t)gB1[j];
            }
            // next-window index loads + monotone segment advance (no binary search)
            const bool more = (et + 32 < eE);
            int nbA2 = 0, nbB2 = 0, sgA2 = sgB, sgB2 = sgB;
            if (more) {
                int erA2 = et + 32 + c; if (erA2 > eE - 1) erA2 = eE - 1;
                int erB2 = et + 48 + c; if (erB2 > eE - 1) erB2 = eE - 1;
                nbA2 = nbr[erA2]; nbB2 = nbr[erB2];
                while (sgA2 < sB - 1 && rsp[sgA2 + 1] <= erA2) ++sgA2;
                sgB2 = sgA2;
                while (sgB2 < sB - 1 && rsp[sgB2 + 1] <= erB2) ++sgB2;
            }
            // GEMM1 tile A (+bias+GELU -> LDS bufA)
            #pragma unroll
            for (int t = 0; t < 8; ++t) {
                f32x4 h = {b1r[t], b1r[t], b1r[t], b1r[t]};
                h = MFMA16(aA0, w1f[t][0], h);
                h = MFMA16(aA1, w1f[t][1], h);
                #pragma unroll
                for (int j = 0; j < 4; ++j)
                    *(bf16_t*)(lds + hwA + j * 272 + t * 32) = (bf16_t)gelu_fast(h[j]);
            }
            // GEMM1 tile B -> LDS bufB
            #pragma unroll
            for (int t = 0; t < 8; ++t) {
                f32x4 h = {b1r[t], b1r[t], b1r[t], b1r[t]};
                h = MFMA16(aB0, w1f[t][0], h);
                h = MFMA16(aB1, w1f[t][1], h);
                #pragma unroll
                for (int j = 0; j < 4; ++j)
                    *(bf16_t*)(lds + hwB + j * 272 + t * 32) = (bf16_t)gelu_fast(h[j]);
            }
            // issue next-window row loads (hide under GEMM2); slf reload only on seg change
            if (more) {
                { const float4_t* p = (const float4_t*)(in_f + (size_t)nbA2 * 32 + 8 * g); fA0 = p[0]; fA1 = p[1]; }
                if (sgA2 != sgA) { const float4_t* p = (const float4_t*)(out_f + (size_t)sgA2 * 32 + 8 * g); gA0 = p[0]; gA1 = p[1]; }
                { const float4_t* p = (const float4_t*)(in_f + (size_t)nbB2 * 32 + 8 * g); fB0 = p[0]; fB1 = p[1]; }
                if (sgB2 != sgB) { const float4_t* p = (const float4_t*)(out_f + (size_t)sgB2 * 32 + 8 * g); gB0 = p[0]; gB1 = p[1]; }
                sgA = sgA2; sgB = sgB2;
            }
            // GEMM2 tile A: ah from LDS bufA, W2 frags from LDS
            {
                bf16x8 ah[4];
                #pragma unroll
                for (int k2 = 0; k2 < 4; ++k2) ah[k2] = *(const bf16x8*)(lds + hrA + k2 * 64);
                f32x4 y[4];
                #pragma unroll
                for (int u = 0; u < 4; ++u) y[u] = (f32x4){0.f, 0.f, 0.f, 0.f};
                #pragma unroll
                for (int u = 0; u < 4; ++u)
                    #pragma unroll
                    for (int k2 = 0; k2 < 4; ++k2) {
                        const bf16x8 w2v = *(const bf16x8*)(lds + (u * 4 + k2) * 1024 + lane * 16);
                        y[u] = MFMA16(ah[k2], w2v, y[u]);
                    }
                accum_close(et, y);
            }
            // GEMM2 tile B
            if (et + 16 < eE) {
                bf16x8 ah[4];
                #pragma unroll
                for (int k2 = 0; k2 < 4; ++k2) ah[k2] = *(const bf16x8*)(lds + hrB + k2 * 64);
                f32x4 y[4];
                #pragma unroll
                for (int u = 0; u < 4; ++u) y[u] = (f32x4){0.f, 0.f, 0.f, 0.f};
                #pragma unroll
                for (int u = 0; u < 4; ++u)
                    #pragma unroll
                    for (int k2 = 0; k2 < 4; ++k2) {
                        const bf16x8 w2v = *(const bf16x8*)(lds + (u * 4 + k2) * 1024 + lane * 16);
                        y[u] = MFMA16(ah[k2], w2v, y[u]);
                    }
                accum_close(et + 16, y);
            }
        }
    }
    // all-empty range tail
    while (s < sB) {
        float* orow = out + (size_t)s * 64;
        if (g == 0) {
            #pragma unroll
            for (int u = 0; u < 4; ++u) orow[u * 16 + c] = 0.0f;
        }
        ++s;
    }
}

extern "C" void kernel_launch(void* const* d_in, const int* in_sizes, int n_in,
                              void* d_out, int out_size, void* d_ws, size_t ws_size,
                              hipStream_t stream) {
    const float* in_f  = (const float*)d_in[0];
    const float* out_f = (const float*)d_in[1];
    const float* W1    = (const float*)d_in[2];
    const float* b1    = (const float*)d_in[3];
    const float* W2    = (const float*)d_in[4];
    const float* b2    = (const float*)d_in[5];
    const int*   nbr   = (const int*)d_in[6];
    const int*   rsp   = (const int*)d_in[7];
    float* out = (float*)d_out;
    const int M = in_sizes[7] - 1;
    const int E = in_sizes[6];

    const int nblocks = 512;              // 2 blocks/CU, 2 waves/SIMD — ILP inside the wave
    const int nwaves  = nblocks * 4;
    const int epw = (E + nwaves - 1) / nwaves;

    nmlp_kernel<<<dim3(nblocks), dim3(256), 0, stream>>>(in_f, out_f, W1, b1, W2, b2,
                                                         nbr, rsp, out, M, E, epw, nwaves);
}